// Round 7
// baseline (141.288 us; speedup 1.0000x reference)
//
#include <hip/hip_runtime.h>

// EfficientPairEmbed: out[0, e, h] = sum_g emb[anum[src_e], anum[dst_e], 0, h, g] * rbf[e, g]
// rbf[e,g] = exp(-0.5/std^2 * (dist_e - offset_g)^2), offsets = linspace(0, 12, 50), std = 12/50.
//
// R11b: R11 resubmit after infra failure, with BKT_CAP 192->160 so the workspace
// requirement (48.1MB) stays under the proven-available 55MB (R8). Theory unchanged:
// rocprof R10 caught the gather at 48.5us, FETCH 72.5MB (= 12MB metadata +
// ~60MB ~= 8MB table x 8 XCDs), 2.4 TB/s effective. Every XCD pulls the whole table
// through its private 4MB L2 -- which is why R7/R8/R9 were all null (they never
// reduced the per-XCD fill). Fix: bucket edges by pair-slice (8 x 1250 pairs = 1MB
// table each) in a build pass fused with the transpose (LDS-local bucketing), then
// gather with block b serving bucket b&7. With round-robin blockIdx->XCD each XCD
// touches only its 1MB L2-resident slice (table fetch 60->8MB, random reads become
// L2 hits). Correct regardless of the actual XCD mapping (any block can serve any
// bucket). Numerics identical (same bf16 table, same window weights): absmax ~0.03125.

#define G_NUM 50
#define H_NUM 8
#define NE_NUM 100
#define N_PAIRS (NE_NUM * NE_NUM)
#define WIN 8
#define BLOCK_THREADS 256
#define TP_PAIRS 8                          // pairs per transpose block
#define T_BLOCKS (N_PAIRS / TP_PAIRS)       // 1250 transpose blocks
#define SEG_EDGES 512                       // edges per partition segment
#define NBKT 8                              // pair-slices == XCD count
#define BKT_CAP 160                         // Binom(512,1/8): mean 64, sigma 7.5 -> 12.8 sigma
#define PAIRS_PER_BKT ((N_PAIRS + NBKT - 1) / NBKT)   // 1250 pairs -> 1MB table slice

#define SPACING (12.0f / (float)(G_NUM - 1))
#define INV_SPACING ((float)(G_NUM - 1) / 12.0f)
#define RBF_COEFF (-0.5f * ((float)G_NUM / 12.0f) * ((float)G_NUM / 12.0f))

typedef float vf4 __attribute__((ext_vector_type(4)));   // native vec for nontemporal stores

__device__ __forceinline__ float bf_lo(unsigned u) { return __uint_as_float(u << 16); }
__device__ __forceinline__ float bf_hi(unsigned u) { return __uint_as_float(u & 0xffff0000u); }

// ---------------- Pass 0 (fused): transpose-cast + edge partition ----------------
// Blocks [0, T_BLOCKS): emb [p][h][g] fp32 -> temb [p][g][h] bf16 (unchanged from R6).
// Blocks [T_BLOCKS, T_BLOCKS+n_seg): bucket 512 edges by pair-slice into records
//   {eid, window short-offset, residual} via LDS counters; coalesced flush.
__global__ __launch_bounds__(BLOCK_THREADS) void build_kernel(
    const float* __restrict__ emb,
    const int* __restrict__ anum,
    const int* __restrict__ edge_index,
    const float* __restrict__ dist,
    unsigned int* __restrict__ temb,
    uint4* __restrict__ recs,              // [n_seg][NBKT][BKT_CAP] 16B records
    unsigned int* __restrict__ hdr,        // [n_seg][NBKT] counts
    int n_edges)
{
    __shared__ float ls[TP_PAIRS * H_NUM * G_NUM];   // 12.8 KB (transpose branch)
    __shared__ unsigned cnt[NBKT];
    __shared__ uint4 rbuf[NBKT][BKT_CAP];            // 20 KB (partition branch)

    const int tid = threadIdx.x;

    if (blockIdx.x < T_BLOCKS) {
        // ---------- transpose-cast branch ----------
        const int p0 = blockIdx.x * TP_PAIRS;
        const float4* src = (const float4*)(emb + (size_t)p0 * (H_NUM * G_NUM));
        #pragma unroll
        for (int i = tid; i < TP_PAIRS * H_NUM * G_NUM / 4; i += BLOCK_THREADS)
            ((float4*)ls)[i] = src[i];
        __syncthreads();

        unsigned int* dst = temb + (size_t)p0 * (H_NUM * G_NUM / 2);
        #pragma unroll
        for (int i = tid; i < TP_PAIRS * H_NUM * G_NUM / 2; i += BLOCK_THREADS) {
            int q  = i / (H_NUM * G_NUM / 2);
            int u  = i - q * (H_NUM * G_NUM / 2);
            int g  = u >> 2;
            int h0 = (u & 3) * 2;
            float f0 = ls[q * (H_NUM * G_NUM) + h0 * G_NUM + g];
            float f1 = ls[q * (H_NUM * G_NUM) + (h0 + 1) * G_NUM + g];
            unsigned u0 = __float_as_uint(f0);
            unsigned u1 = __float_as_uint(f1);
            unsigned b0 = (u0 + 0x7fffu + ((u0 >> 16) & 1u)) >> 16;   // RNE bf16
            unsigned b1 = (u1 + 0x7fffu + ((u1 >> 16) & 1u)) >> 16;
            dst[i] = (b1 << 16) | (b0 & 0xffffu);
        }
        return;
    }

    // ---------- partition branch ----------
    const int seg = blockIdx.x - T_BLOCKS;
    const int e0  = seg * SEG_EDGES;

    if (tid < NBKT) cnt[tid] = 0;
    __syncthreads();

    #pragma unroll
    for (int k = 0; k < SEG_EDGES / BLOCK_THREADS; ++k) {
        int e = e0 + k * BLOCK_THREADS + tid;          // coalesced metadata streams
        if (e < n_edges) {
            int s  = __builtin_nontemporal_load(edge_index + e);
            int d  = __builtin_nontemporal_load(edge_index + n_edges + e);
            float dv = __builtin_nontemporal_load(dist + e);
            int p  = anum[s] * NE_NUM + anum[d];       // anum: 200KB, L2-hit
            int g0 = (int)(dv * INV_SPACING) - 3;
            g0 = g0 < 0 ? 0 : (g0 > G_NUM - WIN ? G_NUM - WIN : g0);
            int bkt = p / PAIRS_PER_BKT;               // 0..7 pair-slice
            unsigned slot = atomicAdd(&cnt[bkt], 1u);
            if (slot < BKT_CAP) {
                uint4 r;
                r.x = (unsigned)e;
                r.y = (unsigned)(p * (G_NUM * H_NUM) + g0 * H_NUM);  // short offset
                r.z = __float_as_uint(dv - (float)g0 * SPACING);     // residual
                r.w = 0;
                rbuf[bkt][slot] = r;
            }
        }
    }
    __syncthreads();

    if (tid < NBKT) {
        unsigned c = cnt[tid];
        hdr[seg * NBKT + tid] = c < BKT_CAP ? c : BKT_CAP;
    }
    // coalesced flush of staged records
    for (int b = 0; b < NBKT; ++b) {
        unsigned c = cnt[b];
        if (c > BKT_CAP) c = BKT_CAP;
        uint4* dst = recs + ((size_t)(seg * NBKT + b)) * BKT_CAP;
        for (unsigned i = tid; i < c; i += BLOCK_THREADS)
            dst[i] = rbuf[b][i];
    }
}

// ---------------- Pass 1: XCD-sliced gather ----------------
// Block b: segment b>>3, bucket b&7. With round-robin blockIdx->XCD, bucket x runs
// on XCD x and only touches temb slice [x*1250 pairs) = 1MB -> L2-resident.
__global__ __launch_bounds__(64) void gather_kernel(
    const unsigned short* __restrict__ temb,
    const uint4* __restrict__ recs,
    const unsigned int* __restrict__ hdr,
    float* __restrict__ out)
{
    const int seg  = blockIdx.x >> 3;
    const int x    = blockIdx.x & 7;
    const int lane = threadIdx.x;

    const unsigned c = hdr[seg * NBKT + x];
    const uint4* base = recs + ((size_t)(seg * NBKT + x)) * BKT_CAP;

    for (unsigned i = lane; i < c; i += 64) {
        uint4 r = base[i];                         // 16B/lane coalesced
        const unsigned eid = r.x;
        const unsigned off = r.y;
        const float res = __uint_as_float(r.z);

        const unsigned short* wb = temb + off;     // within this bucket's 1MB slice
        uint4 v[WIN];
        #pragma unroll
        for (int rr = 0; rr < WIN; ++rr)
            v[rr] = *(const uint4*)(wb + rr * H_NUM);   // 8 x 16B, L2-hit

        float a0 = 0.f, a1 = 0.f, a2 = 0.f, a3 = 0.f;
        float a4 = 0.f, a5 = 0.f, a6 = 0.f, a7 = 0.f;
        #pragma unroll
        for (int rr = 0; rr < WIN; ++rr) {
            float diff = res - (float)rr * SPACING;
            float rb = __expf(RBF_COEFF * diff * diff);
            a0 += rb * bf_lo(v[rr].x);  a1 += rb * bf_hi(v[rr].x);
            a2 += rb * bf_lo(v[rr].y);  a3 += rb * bf_hi(v[rr].y);
            a4 += rb * bf_lo(v[rr].z);  a5 += rb * bf_hi(v[rr].z);
            a6 += rb * bf_lo(v[rr].w);  a7 += rb * bf_hi(v[rr].w);
        }

        // scattered 32B store; nontemporal so it can't evict the table slice
        float* ob = out + (size_t)eid * H_NUM;
        vf4 lo = {a0, a1, a2, a3};
        vf4 hi = {a4, a5, a6, a7};
        __builtin_nontemporal_store(lo, (vf4*)ob);
        __builtin_nontemporal_store(hi, (vf4*)(ob + 4));
    }
}

// ---------------- Fallback (ws-free): exact fp32 direct kernel ----------------
__global__ __launch_bounds__(BLOCK_THREADS) void direct_kernel(
    const int* __restrict__ anum,
    const int* __restrict__ edge_index,
    const float* __restrict__ dist,
    const float* __restrict__ emb,
    float* __restrict__ out,
    int n_edges)
{
    __shared__ int   pair_s[32];
    __shared__ float dist_sd[32];
    __shared__ float rbf_sd[32 * G_NUM];

    const int tid = threadIdx.x;
    const int e0  = blockIdx.x * 32;

    if (tid < 32) {
        int e = e0 + tid;
        if (e >= n_edges) e = n_edges - 1;
        int s  = edge_index[e];
        int d  = edge_index[n_edges + e];
        pair_s[tid] = (anum[s] * NE_NUM + anum[d]) * (H_NUM * G_NUM);
        dist_sd[tid] = dist[e];
    }
    __syncthreads();

    for (int idx = tid; idx < 32 * G_NUM; idx += BLOCK_THREADS) {
        int el = idx / G_NUM;
        int g  = idx - el * G_NUM;
        float diff = dist_sd[el] - (float)g * SPACING;
        rbf_sd[idx] = __expf(RBF_COEFF * diff * diff);
    }
    __syncthreads();

    const int el = tid >> 3;
    const int h  = tid & 7;
    const float* ebase = emb + pair_s[el] + h * G_NUM;
    const float* rbase = rbf_sd + el * G_NUM;

    float acc = 0.0f;
    #pragma unroll
    for (int g2 = 0; g2 < G_NUM / 2; ++g2) {
        float2 ev = *(const float2*)(ebase + 2 * g2);
        float2 rv = *(const float2*)(rbase + 2 * g2);
        acc += ev.x * rv.x + ev.y * rv.y;
    }

    if (e0 + el < n_edges)
        out[e0 * H_NUM + tid] = acc;
}

extern "C" void kernel_launch(void* const* d_in, const int* in_sizes, int n_in,
                              void* d_out, int out_size, void* d_ws, size_t ws_size,
                              hipStream_t stream) {
    const int*   anum       = (const int*)d_in[0];
    const int*   edge_index = (const int*)d_in[1];
    const float* dist       = (const float*)d_in[2];
    const float* emb        = (const float*)d_in[3];
    float*       out        = (float*)d_out;
    const int n_edges = in_sizes[2];

    const size_t temb_bytes = (size_t)N_PAIRS * H_NUM * G_NUM * sizeof(unsigned short); // 8 MB
    const int    n_seg      = (n_edges + SEG_EDGES - 1) / SEG_EDGES;
    const size_t recs_bytes = (size_t)n_seg * NBKT * BKT_CAP * sizeof(uint4);           // ~40 MB
    const size_t hdr_bytes  = (size_t)n_seg * NBKT * sizeof(unsigned int);
    const size_t need       = temb_bytes + recs_bytes + hdr_bytes;                      // ~48.1 MB

    if (ws_size < need) {
        const int grid = (n_edges + 31) / 32;
        direct_kernel<<<grid, BLOCK_THREADS, 0, stream>>>(
            anum, edge_index, dist, emb, out, n_edges);
        return;
    }

    unsigned int* temb = (unsigned int*)d_ws;
    uint4*        recs = (uint4*)((char*)d_ws + temb_bytes);            // 16B-aligned (8e6 % 16 == 0)
    unsigned int* hdr  = (unsigned int*)((char*)d_ws + temb_bytes + recs_bytes);

    build_kernel<<<T_BLOCKS + n_seg, BLOCK_THREADS, 0, stream>>>(
        emb, anum, edge_index, dist, temb, recs, hdr, n_edges);

    gather_kernel<<<n_seg * NBKT, 64, 0, stream>>>(
        (const unsigned short*)temb, recs, hdr, out);
}

// Round 8
// 114.377 us; speedup vs baseline: 1.2353x; 1.2353x over previous
//
#include <hip/hip_runtime.h>

// EfficientPairEmbed: out[0, e, h] = sum_g emb[anum[src_e], anum[dst_e], 0, h, g] * rbf[e, g]
// rbf[e,g] = exp(-0.5/std^2 * (dist_e - offset_g)^2), offsets = linspace(0, 12, 50), std = 12/50.
//
// R12: REVERT to the best-measured structure (Round-0 baseline, 112.8us; reproduced
// 115.3us). Session post-mortem: the gather is pinned at ~43-49us under SIX orthogonal
// structural transforms -- R7 coalescing (4x fewer tx), R8 aligned 1-line windows
// (1.9x fewer lines), R9 temporal slicing, R10 2-edge ILP, R11b XCD-routing (FETCH
// 72.5 -> 12.65MB, all reads L2-resident, time UNCHANGED). Conclusion: bound by a
// per-CU divergent-access processing floor (~30 cyc/edge/CU in the vector-memory
// pipe), not by bytes/lines/tx at any cache tier. WIN=8 is the numeric minimum
// (WIN=6 dropped-term error ~0.13 > passing absmax 0.031). Remaining total =
// harness poison fills (46-92us) + build ~7us (stream floor) + gather ~48us
// (divergent-access floor) + launch misc. This is the roofline configuration.

#define G_NUM 50
#define H_NUM 8
#define NE_NUM 100
#define N_PAIRS (NE_NUM * NE_NUM)
#define WIN 8
#define BLOCK_THREADS 256
#define TP_PAIRS 8               // pairs per transpose block

#define SPACING (12.0f / (float)(G_NUM - 1))
#define INV_SPACING ((float)(G_NUM - 1) / 12.0f)
#define RBF_COEFF (-0.5f * ((float)G_NUM / 12.0f) * ((float)G_NUM / 12.0f))

__device__ __forceinline__ float bf_lo(unsigned u) { return __uint_as_float(u << 16); }
__device__ __forceinline__ float bf_hi(unsigned u) { return __uint_as_float(u & 0xffff0000u); }

// ---------------- Pass 0: emb [p][h][g] fp32 -> temb [p][g][h] bf16, LDS-staged ----------------
__global__ __launch_bounds__(BLOCK_THREADS) void transpose_cast_kernel(
    const float* __restrict__ emb, unsigned int* __restrict__ temb)
{
    __shared__ float ls[TP_PAIRS * H_NUM * G_NUM];          // 3200 floats, 12.8 KB

    const int tid = threadIdx.x;
    const int p0  = blockIdx.x * TP_PAIRS;

    // Coalesced read: 800 float4 per block.
    const float4* src = (const float4*)(emb + (size_t)p0 * (H_NUM * G_NUM));
    #pragma unroll
    for (int i = tid; i < TP_PAIRS * H_NUM * G_NUM / 4; i += BLOCK_THREADS)
        ((float4*)ls)[i] = src[i];
    __syncthreads();

    // Coalesced write: 1600 packed-bf16 uints per block.
    unsigned int* dst = temb + (size_t)p0 * (H_NUM * G_NUM / 2);
    #pragma unroll
    for (int i = tid; i < TP_PAIRS * H_NUM * G_NUM / 2; i += BLOCK_THREADS) {
        int q  = i / (H_NUM * G_NUM / 2);          // local pair
        int u  = i - q * (H_NUM * G_NUM / 2);      // uint idx within pair: [g][h/2]
        int g  = u >> 2;
        int h0 = (u & 3) * 2;
        float f0 = ls[q * (H_NUM * G_NUM) + h0 * G_NUM + g];
        float f1 = ls[q * (H_NUM * G_NUM) + (h0 + 1) * G_NUM + g];
        unsigned u0 = __float_as_uint(f0);
        unsigned u1 = __float_as_uint(f1);
        unsigned b0 = (u0 + 0x7fffu + ((u0 >> 16) & 1u)) >> 16;   // RNE bf16
        unsigned b1 = (u1 + 0x7fffu + ((u1 >> 16) & 1u)) >> 16;
        dst[i] = (b1 << 16) | (b0 & 0xffffu);
    }
}

// ---------------- Pass 1: direct windowed gather, 1 lane/edge ----------------
__global__ __launch_bounds__(BLOCK_THREADS) void gather_kernel(
    const int* __restrict__ anum,
    const int* __restrict__ edge_index,
    const float* __restrict__ dist,
    const unsigned short* __restrict__ temb,
    float* __restrict__ out,
    int n_edges)
{
    int e = blockIdx.x * BLOCK_THREADS + threadIdx.x;
    if (e >= n_edges) return;

    int s = edge_index[e];
    int d = edge_index[n_edges + e];
    int p = anum[s] * NE_NUM + anum[d];
    float dv = dist[e];

    int g0 = (int)(dv * INV_SPACING) - 3;
    if (g0 < 0) g0 = 0;
    if (g0 > G_NUM - WIN) g0 = G_NUM - WIN;

    // Window rows are 16B each ([g][h0..7] bf16), 128B contiguous total.
    const unsigned short* wb = temb + (size_t)p * (H_NUM * G_NUM) + g0 * H_NUM;

    uint4 v[WIN];
    #pragma unroll
    for (int r = 0; r < WIN; ++r)
        v[r] = *(const uint4*)(wb + r * H_NUM);      // 8 independent 16B loads

    float a0 = 0.f, a1 = 0.f, a2 = 0.f, a3 = 0.f;
    float a4 = 0.f, a5 = 0.f, a6 = 0.f, a7 = 0.f;
    #pragma unroll
    for (int r = 0; r < WIN; ++r) {
        float diff = dv - (float)(g0 + r) * SPACING;
        float rb = __expf(RBF_COEFF * diff * diff);
        a0 += rb * bf_lo(v[r].x);
        a1 += rb * bf_hi(v[r].x);
        a2 += rb * bf_lo(v[r].y);
        a3 += rb * bf_hi(v[r].y);
        a4 += rb * bf_lo(v[r].z);
        a5 += rb * bf_hi(v[r].z);
        a6 += rb * bf_lo(v[r].w);
        a7 += rb * bf_hi(v[r].w);
    }

    float* ob = out + (size_t)e * H_NUM;
    *(float4*)(ob)     = make_float4(a0, a1, a2, a3);   // coalesced 32B/thread
    *(float4*)(ob + 4) = make_float4(a4, a5, a6, a7);
}

// ---------------- Fallback (ws-free): exact fp32 direct kernel ----------------
__global__ __launch_bounds__(BLOCK_THREADS) void direct_kernel(
    const int* __restrict__ anum,
    const int* __restrict__ edge_index,
    const float* __restrict__ dist,
    const float* __restrict__ emb,
    float* __restrict__ out,
    int n_edges)
{
    __shared__ int   pair_s[32];
    __shared__ float dist_sd[32];
    __shared__ float rbf_sd[32 * G_NUM];

    const int tid = threadIdx.x;
    const int e0  = blockIdx.x * 32;

    if (tid < 32) {
        int e = e0 + tid;
        if (e >= n_edges) e = n_edges - 1;
        int s  = edge_index[e];
        int d  = edge_index[n_edges + e];
        pair_s[tid] = (anum[s] * NE_NUM + anum[d]) * (H_NUM * G_NUM);
        dist_sd[tid] = dist[e];
    }
    __syncthreads();

    for (int idx = tid; idx < 32 * G_NUM; idx += BLOCK_THREADS) {
        int el = idx / G_NUM;
        int g  = idx - el * G_NUM;
        float diff = dist_sd[el] - (float)g * SPACING;
        rbf_sd[idx] = __expf(RBF_COEFF * diff * diff);
    }
    __syncthreads();

    const int el = tid >> 3;
    const int h  = tid & 7;
    const float* ebase = emb + pair_s[el] + h * G_NUM;
    const float* rbase = rbf_sd + el * G_NUM;

    float acc = 0.0f;
    #pragma unroll
    for (int g2 = 0; g2 < G_NUM / 2; ++g2) {
        float2 ev = *(const float2*)(ebase + 2 * g2);
        float2 rv = *(const float2*)(rbase + 2 * g2);
        acc += ev.x * rv.x + ev.y * rv.y;
    }

    if (e0 + el < n_edges)
        out[e0 * H_NUM + tid] = acc;
}

extern "C" void kernel_launch(void* const* d_in, const int* in_sizes, int n_in,
                              void* d_out, int out_size, void* d_ws, size_t ws_size,
                              hipStream_t stream) {
    const int*   anum       = (const int*)d_in[0];
    const int*   edge_index = (const int*)d_in[1];
    const float* dist       = (const float*)d_in[2];
    const float* emb        = (const float*)d_in[3];
    float*       out        = (float*)d_out;
    const int n_edges = in_sizes[2];

    const size_t temb_bytes = (size_t)N_PAIRS * H_NUM * G_NUM * sizeof(unsigned short); // 8 MB

    if (ws_size < temb_bytes) {
        const int grid = (n_edges + 31) / 32;
        direct_kernel<<<grid, BLOCK_THREADS, 0, stream>>>(
            anum, edge_index, dist, emb, out, n_edges);
        return;
    }

    unsigned int* temb = (unsigned int*)d_ws;

    transpose_cast_kernel<<<N_PAIRS / TP_PAIRS, BLOCK_THREADS, 0, stream>>>(emb, temb);

    const int grid = (n_edges + BLOCK_THREADS - 1) / BLOCK_THREADS;
    gather_kernel<<<grid, BLOCK_THREADS, 0, stream>>>(
        anum, edge_index, dist, (const unsigned short*)temb, out, n_edges);
}